// Round 14
// baseline (166.625 us; speedup 1.0000x reference)
//
#include <hip/hip_runtime.h>

#define B 2
#define N_P 2000
#define N_ALL 2048
#define N_REL 8192
#define N_INST 8
#define NF 128
#define DEG_CAP 64

typedef unsigned short u16;
typedef __attribute__((ext_vector_type(8))) short bf16x8;
typedef __attribute__((ext_vector_type(4))) float f32x4;

__device__ __forceinline__ u16 f2bf(float f) {
    union { float f; unsigned u; } v; v.f = f;
    unsigned r = v.u + 0x7FFFu + ((v.u >> 16) & 1u);
    return (u16)(r >> 16);
}
__device__ __forceinline__ float bf2f(u16 h) {
    union { unsigned u; float f; } v; v.u = ((unsigned)h) << 16; return v.f;
}

#define MFMA16(a, b, c) __builtin_amdgcn_mfma_f32_16x16x32_bf16((a), (b), (c), 0, 0, 0)
#define SWZ(row, col) ((col) ^ (((row) & 7) << 3))

#define NWT 13
struct WtCvt {
    const float* src[NWT];
    int K[NWT];
    int Kpad[NWT];
    int cum[NWT + 1];
};

// ---------------------------------------------------------------------------
// D1: scan_h0: [0,8192) rows' first half unconditional; weight cvt; p_inputs.
// ---------------------------------------------------------------------------
#define H0_SCAN_BLKS 8192
#define H0_CVT_BLKS  752
#define H0_PIN_BLKS  16
#define H0_TOTAL (H0_SCAN_BLKS + H0_CVT_BLKS + H0_PIN_BLKS)

__global__ __launch_bounds__(256) void scan_h0(
    const float* __restrict__ Rr, const float* __restrict__ Rs,
    int* __restrict__ rr, int* __restrict__ rs,
    WtCvt d, u16* __restrict__ wt, int wt_total,
    const float* __restrict__ state, const float* __restrict__ attrs,
    const float* __restrict__ action, const float* __restrict__ den,
    const float* __restrict__ phys, u16* __restrict__ P)
{
    int blk = blockIdx.x;
    if (blk < H0_SCAN_BLKS) {
        int lane = threadIdx.x & 63;
        int r = blk * 4 + (threadIdx.x >> 6);
        const float* base = (r < 16384 ? Rr + (size_t)r * N_ALL
                                       : Rs + (size_t)(r - 16384) * N_ALL);
        const f32x4* s = reinterpret_cast<const f32x4*>(base) + lane;
        f32x4 v[4];
        #pragma unroll
        for (int i = 0; i < 4; ++i) v[i] = s[64 * i];
        int f = -1;
        #pragma unroll
        for (int i = 0; i < 4; ++i) {
            int bi = (lane + 64 * i) * 4;
            if (v[i].x != 0.f) f = bi;
            if (v[i].y != 0.f) f = bi + 1;
            if (v[i].z != 0.f) f = bi + 2;
            if (v[i].w != 0.f) f = bi + 3;
        }
        #pragma unroll
        for (int off = 32; off; off >>= 1) f = max(f, __shfl_xor(f, off));
        if (lane == 0) {
            int* outp = (r < 16384) ? rr : rs;
            outp[r & 16383] = f;
        }
        return;
    }
    blk -= H0_SCAN_BLKS;
    if (blk < H0_CVT_BLKS) {
        int t = blk * 256 + threadIdx.x;
        if (t >= wt_total) return;
        int m = 0;
        while (t >= d.cum[m + 1]) m++;
        int loc = t - d.cum[m];
        int Kp = d.Kpad[m];
        int c = loc / Kp, k = loc - c * Kp;
        float v = (k < d.K[m]) ? d.src[m][(size_t)k * NF + c] : 0.f;
        wt[t] = f2bf(v);
        return;
    }
    blk -= H0_CVT_BLKS;
    {
        int t = blk * 256 + threadIdx.x;
        if (t >= B * N_ALL) return;
        int b = t >> 11, n = t & 2047;
        float o[19];
        o[0] = attrs[t * 2]; o[1] = attrs[t * 2 + 1];
        #pragma unroll
        for (int h = 0; h < 3; ++h)
            #pragma unroll
            for (int c = 0; c < 3; ++c)
                o[2 + h * 3 + c] = state[(((size_t)b * 4 + h + 1) * N_ALL + n) * 3 + c]
                                 - state[(((size_t)b * 4 + h)     * N_ALL + n) * 3 + c];
        #pragma unroll
        for (int c = 0; c < 3; ++c)
            o[11 + c] = state[(((size_t)b * 4 + 3) * N_ALL + n) * 3 + c];
        o[14] = (n < N_P) ? phys[b] : 0.f;
        #pragma unroll
        for (int c = 0; c < 3; ++c) o[15 + c] = action[t * 3 + c];
        o[18] = (n < N_P) ? den[b] : 0.f;
        u16* dst = P + (size_t)t * 32;
        #pragma unroll
        for (int k = 0; k < 19; ++k) dst[k] = f2bf(o[k]);
        #pragma unroll
        for (int k = 19; k < 32; ++k) dst[k] = 0;
    }
}

// ---------------------------------------------------------------------------
// D2/D3: conditional 512-float stripe scans; blocks >= 8192 zero cnt + bar.
// ---------------------------------------------------------------------------
template<int START>
__global__ __launch_bounds__(256) void scan_stripe(
    const float* __restrict__ Rr, const float* __restrict__ Rs,
    int* __restrict__ rr, int* __restrict__ rs,
    int* __restrict__ cnt, int* __restrict__ bar)
{
    if (blockIdx.x >= 8192) {
        int t = (blockIdx.x - 8192) * 256 + threadIdx.x;
        if (t < B * N_ALL) cnt[t] = 0;
        if (t == 0) *bar = 0;
        return;
    }
    int lane = threadIdx.x & 63;
    int r = blockIdx.x * 4 + (threadIdx.x >> 6);
    int* outp = (r < 16384) ? rr : rs;
    int e = r & 16383;
    if (outp[e] >= 0) return;
    const float* base = ((r < 16384) ? Rr + (size_t)r * N_ALL
                                     : Rs + (size_t)(r - 16384) * N_ALL) + START;
    const f32x4* s = reinterpret_cast<const f32x4*>(base + lane * 8);
    f32x4 v0 = s[0], v1 = s[1];
    int f = -1;
    int bi = START + lane * 8;
    #pragma unroll
    for (int j = 0; j < 4; ++j) {
        if (v0[j] != 0.f) f = bi + j;
        if (v1[j] != 0.f) f = bi + 4 + j;
    }
    #pragma unroll
    for (int off = 32; off; off >>= 1) f = max(f, __shfl_xor(f, off));
    if (lane == 0) outp[e] = f;
}

// ---------------------------------------------------------------------------
// Shared layer helpers (wave = 16 rows x 128 cols)
// ---------------------------------------------------------------------------
__device__ __forceinline__ void ldsA_gemm(const u16* T, const u16* __restrict__ wtm,
                                          f32x4 acc[8], int r16, int g4)
{
    #pragma unroll
    for (int cf = 0; cf < 8; ++cf) acc[cf] = (f32x4){0.f, 0.f, 0.f, 0.f};
    #pragma unroll
    for (int kf = 0; kf < 4; ++kf) {
        int kcol = kf * 32 + g4 * 8;
        bf16x8 a = *reinterpret_cast<const bf16x8*>(&T[r16 * NF + SWZ(r16, kcol)]);
        #pragma unroll
        for (int cf = 0; cf < 8; ++cf) {
            bf16x8 bv = *reinterpret_cast<const bf16x8*>(wtm + (size_t)(cf * 16 + r16) * NF + kcol);
            acc[cf] = MFMA16(a, bv, acc[cf]);
        }
    }
}
__device__ __forceinline__ void tile_store(u16* T, f32x4 acc[8], const float* __restrict__ bias,
                                           int r16, int g4)
{
    #pragma unroll
    for (int cf = 0; cf < 8; ++cf) {
        float bb = bias[cf * 16 + r16];
        #pragma unroll
        for (int i = 0; i < 4; ++i) {
            int row = g4 * 4 + i, col = cf * 16 + r16;
            T[row * NF + SWZ(row, col)] = f2bf(fmaxf(acc[cf][i] + bb, 0.f));
        }
    }
}

// ---------------------------------------------------------------------------
// ENC2 (unchanged from round 12): rel enc [0,256) | part enc [256,320) |
// bucket fill [320,328)
// ---------------------------------------------------------------------------
#define ENC_REL_BLKS 256
#define ENC_PART_BLKS 64
#define ENC_FILL_BLKS 8
#define ENC_TOTAL (ENC_REL_BLKS + ENC_PART_BLKS + ENC_FILL_BLKS)

__global__ __launch_bounds__(256) void enc2(
    const u16* __restrict__ P, const float* __restrict__ attrs,
    const float* __restrict__ p_inst,
    const int* __restrict__ rr, const int* __restrict__ rs,
    const u16* __restrict__ wpe0, const u16* __restrict__ wpe1, const u16* __restrict__ wpe2,
    const float* __restrict__ pb0, const float* __restrict__ pb1, const float* __restrict__ pb2,
    const u16* __restrict__ wre0, const u16* __restrict__ wre1, const u16* __restrict__ wre2,
    const float* __restrict__ rb0, const float* __restrict__ rb1, const float* __restrict__ rb2,
    const float* __restrict__ rp_b, const u16* __restrict__ wrp0t,
    const u16* __restrict__ wpp0t, const u16* __restrict__ wrp1t, const u16* __restrict__ wrp2t,
    u16* __restrict__ penc, u16* __restrict__ relencW,
    float* __restrict__ Zp, u16* __restrict__ Zrs0,
    int* __restrict__ cnt, int2* __restrict__ buckets)
{
    __shared__ __align__(16) char smem[40960];
    int tid = threadIdx.x;
    int blk = blockIdx.x;

    if (blk >= ENC_REL_BLKS + ENC_PART_BLKS) {
        int t = (blk - ENC_REL_BLKS - ENC_PART_BLKS) * 256 + tid;
        for (int e = t; e < B * N_REL; e += ENC_FILL_BLKS * 256) {
            int n = ((e >> 13) << 11) + rr[e];
            int pos = atomicAdd(&cnt[n], 1);
            if (pos < DEG_CAP) {
                int2 v; v.x = e; v.y = ((e >> 13) << 11) + rs[e];
                buckets[(size_t)n * DEG_CAP + pos] = v;
            }
        }
        return;
    }

    u16* ri = (u16*)smem;
    int w = tid >> 6, lane = tid & 63;
    int r16 = lane & 15, g4 = lane >> 4;
    u16* T0 = (u16*)(smem + 8192 + w * 8192);
    u16* T1 = T0 + 2048;
    f32x4 acc[8];

    if (blk < ENC_REL_BLKS) {
        {
            int row = tid >> 2;
            int q = tid & 3;
            int grow = blk * 64 + row;
            int b = grow >> 13;
            int ir = rr[grow], is_ = rs[grow];
            const u16* pr = P + ((size_t)(b << 11) + ir) * 32;
            const u16* ps = P + ((size_t)(b << 11) + is_) * 32;
            float gd = 0.f;
            if (q == 2) {
                #pragma unroll
                for (int k = 0; k < N_INST; ++k) {
                    float gr = (ir < N_P) ? p_inst[((size_t)b * N_P + ir) * N_INST + k] : 0.f;
                    float gs = (is_ < N_P) ? p_inst[((size_t)b * N_P + is_) * N_INST + k] : 0.f;
                    gd += fabsf(gr - gs);
                }
            }
            #pragma unroll
            for (int j = 0; j < 16; ++j) {
                int c = q * 16 + j;
                u16 hv;
                if (c < 19)       hv = pr[c];
                else if (c < 38)  hv = ps[c - 19];
                else if (c < 40)  hv = f2bf(attrs[((size_t)(b << 11) + ir) * 2 + (c - 38)]);
                else if (c < 42)  hv = f2bf(attrs[((size_t)(b << 11) + is_) * 2 + (c - 40)]);
                else if (c == 42) hv = f2bf(gd);
                else if (c < 55)  hv = f2bf(bf2f(pr[c - 41]) - bf2f(ps[c - 41]));
                else if (c == 55) hv = f2bf(bf2f(pr[18]) - bf2f(ps[18]));
                else              hv = 0;
                ri[row * 64 + SWZ(row, c)] = hv;
            }
        }
        __syncthreads();
        int rbase = blk * 64 + w * 16;
        #pragma unroll
        for (int cf = 0; cf < 8; ++cf) acc[cf] = (f32x4){0.f, 0.f, 0.f, 0.f};
        #pragma unroll
        for (int kf = 0; kf < 2; ++kf) {
            int kcol = kf * 32 + g4 * 8;
            int lr = w * 16 + r16;
            bf16x8 a = *reinterpret_cast<const bf16x8*>(&ri[lr * 64 + SWZ(lr, kcol)]);
            #pragma unroll
            for (int cf = 0; cf < 8; ++cf) {
                bf16x8 bv = *reinterpret_cast<const bf16x8*>(wre0 + (size_t)(cf * 16 + r16) * 64 + kcol);
                acc[cf] = MFMA16(a, bv, acc[cf]);
            }
        }
        tile_store(T0, acc, rb0, r16, g4);
        ldsA_gemm(T0, wre1, acc, r16, g4);
        tile_store(T1, acc, rb1, r16, g4);
        ldsA_gemm(T1, wre2, acc, r16, g4);
        tile_store(T0, acc, rb2, r16, g4);
        ldsA_gemm(T0, wrp0t, acc, r16, g4);
        #pragma unroll
        for (int cf = 0; cf < 8; ++cf) {
            float bb = rp_b[cf * 16 + r16];
            #pragma unroll
            for (int i = 0; i < 4; ++i) {
                int grow = rbase + g4 * 4 + i;
                relencW[(size_t)grow * NF + cf * 16 + r16] = f2bf(acc[cf][i] + bb);
            }
        }
        return;
    }

    int blk2 = blk - ENC_REL_BLKS;
    int rbase = blk2 * 64 + w * 16;
    #pragma unroll
    for (int cf = 0; cf < 8; ++cf) acc[cf] = (f32x4){0.f, 0.f, 0.f, 0.f};
    {
        int kcol = g4 * 8;
        bf16x8 a = *reinterpret_cast<const bf16x8*>(P + (size_t)(rbase + r16) * 32 + kcol);
        #pragma unroll
        for (int cf = 0; cf < 8; ++cf) {
            bf16x8 bv = *reinterpret_cast<const bf16x8*>(wpe0 + (size_t)(cf * 16 + r16) * 32 + kcol);
            acc[cf] = MFMA16(a, bv, acc[cf]);
        }
    }
    tile_store(T0, acc, pb0, r16, g4);
    ldsA_gemm(T0, wpe1, acc, r16, g4);
    tile_store(T1, acc, pb1, r16, g4);
    ldsA_gemm(T1, wpe2, acc, r16, g4);
    tile_store(T0, acc, pb2, r16, g4);
    #pragma unroll
    for (int cf = 0; cf < 8; ++cf)
        #pragma unroll
        for (int i = 0; i < 4; ++i) {
            int row = g4 * 4 + i, col = cf * 16 + r16;
            penc[(size_t)(rbase + row) * NF + col] = T0[row * NF + SWZ(row, col)];
        }
    ldsA_gemm(T0, wpp0t, acc, r16, g4);
    #pragma unroll
    for (int cf = 0; cf < 8; ++cf)
        #pragma unroll
        for (int i = 0; i < 4; ++i)
            Zp[(size_t)(rbase + g4 * 4 + i) * NF + cf * 16 + r16] = acc[cf][i];
    ldsA_gemm(T0, wrp1t, acc, r16, g4);
    #pragma unroll
    for (int cf = 0; cf < 8; ++cf)
        #pragma unroll
        for (int i = 0; i < 4; ++i)
            Zrs0[(size_t)(rbase + g4 * 4 + i) * 256 + cf * 16 + r16] = f2bf(acc[cf][i]);
    ldsA_gemm(T0, wrp2t, acc, r16, g4);
    #pragma unroll
    for (int cf = 0; cf < 8; ++cf)
        #pragma unroll
        for (int i = 0; i < 4; ++i)
            Zrs0[(size_t)(rbase + g4 * 4 + i) * 256 + 128 + cf * 16 + r16] = f2bf(acc[cf][i]);
}

// ---------------------------------------------------------------------------
// STEP_M: three propagation steps in ONE kernel, 128 blocks (guaranteed
// co-resident: 128 < 256 CUs, nothing else on device). Hand-rolled grid
// barrier: monotonic device-scope atomic counter + threadfence.
// ---------------------------------------------------------------------------
struct StepP {
    const int* cnt; const int2* buckets;
    const u16* relencW; const float* Zp; const float* pp_b;
    const u16* wpp1t; const u16* wrp1t; const u16* wrp2t;
    const u16 *wnp0t, *wnp1t; const float *nb0, *nb1;
    const float* np_W2; const float* nb2;
    const float* state; float* out;
    const u16* penc; u16 *effX, *effY, *ZrsA, *ZrsB;
    int* bar;
};

__device__ __forceinline__ void grid_bar(int* bar, int expected)
{
    __syncthreads();
    if (threadIdx.x == 0) {
        __threadfence();
        atomicAdd(bar, 1);
        while (atomicAdd(bar, 0) < expected) { }
        __threadfence();
    }
    __syncthreads();
}

template<int LAST>
__device__ void step_body(const StepP& p,
                          float (*aggL)[NF], u16* twbase,
                          const u16* Zrs, const u16* eff_prev,
                          u16* eff_out, u16* Zrs_out)
{
    int w = threadIdx.x >> 6, lane = threadIdx.x & 63;
    int r16 = lane & 15, g4 = lane >> 4;
    int nbase = blockIdx.x * 32;

    {
        int ln = threadIdx.x >> 3;
        int q  = threadIdx.x & 7;
        int n  = nbase + ln;
        const u16* zrp = Zrs + (size_t)n * 256 + q * 16;
        bf16x8 z0 = *reinterpret_cast<const bf16x8*>(zrp);
        bf16x8 z1 = *reinterpret_cast<const bf16x8*>(zrp + 8);
        float zr[16];
        #pragma unroll
        for (int j = 0; j < 8; ++j) { zr[j] = bf2f((u16)z0[j]); zr[8 + j] = bf2f((u16)z1[j]); }
        float a16[16];
        #pragma unroll
        for (int j = 0; j < 16; ++j) a16[j] = 0.f;
        int k1 = min(p.cnt[n], DEG_CAP);
        const int2* eb_base = p.buckets + (size_t)n * DEG_CAP;
        for (int k = 0; k < k1; k += 4) {
            int m = k1 - k;
            int2 eb[4];
            #pragma unroll
            for (int t = 0; t < 4; ++t) if (t < m) eb[t] = eb_base[k + t];
            #pragma unroll
            for (int t = 0; t < 4; ++t) if (t < m) {
                const u16* rwp = p.relencW + (size_t)eb[t].x * NF + q * 16;
                const u16* zsp = Zrs + (size_t)eb[t].y * 256 + 128 + q * 16;
                bf16x8 rw0 = *reinterpret_cast<const bf16x8*>(rwp);
                bf16x8 rw1 = *reinterpret_cast<const bf16x8*>(rwp + 8);
                bf16x8 zs0 = *reinterpret_cast<const bf16x8*>(zsp);
                bf16x8 zs1 = *reinterpret_cast<const bf16x8*>(zsp + 8);
                #pragma unroll
                for (int j = 0; j < 8; ++j) {
                    a16[j]     += fmaxf(bf2f((u16)rw0[j]) + zr[j]     + bf2f((u16)zs0[j]), 0.f);
                    a16[8 + j] += fmaxf(bf2f((u16)rw1[j]) + zr[8 + j] + bf2f((u16)zs1[j]), 0.f);
                }
            }
        }
        int c0 = q * 16;
        int pc0 = c0 ^ ((ln & 7) << 3);
        int pc1 = (c0 + 8) ^ ((ln & 7) << 3);
        #pragma unroll
        for (int j = 0; j < 8; ++j) {
            aggL[ln][pc0 + j] = a16[j];
            aggL[ln][pc1 + j] = a16[8 + j];
        }
    }
    __syncthreads();
    if (w < 2) {
        u16* T0 = twbase + w * 4096;
        u16* T1 = T0 + 2048;
        f32x4 acc[8];
        #pragma unroll
        for (int cf = 0; cf < 8; ++cf) acc[cf] = (f32x4){0.f, 0.f, 0.f, 0.f};
        int lrow = w * 16 + r16;
        #pragma unroll
        for (int kf = 0; kf < 4; ++kf) {
            int kcol = kf * 32 + g4 * 8;
            int pc = kcol ^ ((lrow & 7) << 3);
            float4 lo = *reinterpret_cast<const float4*>(&aggL[lrow][pc]);
            float4 hi = *reinterpret_cast<const float4*>(&aggL[lrow][pc + 4]);
            bf16x8 a;
            a[0] = (short)f2bf(lo.x); a[1] = (short)f2bf(lo.y);
            a[2] = (short)f2bf(lo.z); a[3] = (short)f2bf(lo.w);
            a[4] = (short)f2bf(hi.x); a[5] = (short)f2bf(hi.y);
            a[6] = (short)f2bf(hi.z); a[7] = (short)f2bf(hi.w);
            #pragma unroll
            for (int cf = 0; cf < 8; ++cf) {
                bf16x8 bv = *reinterpret_cast<const bf16x8*>(p.wpp1t + (size_t)(cf * 16 + r16) * NF + kcol);
                acc[cf] = MFMA16(a, bv, acc[cf]);
            }
        }
        int rbase = nbase + w * 16;
        #pragma unroll
        for (int cf = 0; cf < 8; ++cf) {
            int col = cf * 16 + r16;
            float bb = p.pp_b[col];
            #pragma unroll
            for (int i = 0; i < 4; ++i) {
                int trow = g4 * 4 + i;
                int grow = rbase + trow;
                float v = acc[cf][i] + bb + p.Zp[(size_t)grow * NF + col]
                        + bf2f(eff_prev[(size_t)grow * NF + col]);
                u16 hv = f2bf(fmaxf(v, 0.f));
                T0[trow * NF + SWZ(trow, col)] = hv;
                if (!LAST) eff_out[(size_t)grow * NF + col] = hv;
            }
        }
        if (!LAST) {
            f32x4 acc2[8];
            ldsA_gemm(T0, p.wrp1t, acc2, r16, g4);
            #pragma unroll
            for (int cf = 0; cf < 8; ++cf)
                #pragma unroll
                for (int i = 0; i < 4; ++i)
                    Zrs_out[(size_t)(rbase + g4 * 4 + i) * 256 + cf * 16 + r16] = f2bf(acc2[cf][i]);
            ldsA_gemm(T0, p.wrp2t, acc2, r16, g4);
            #pragma unroll
            for (int cf = 0; cf < 8; ++cf)
                #pragma unroll
                for (int i = 0; i < 4; ++i)
                    Zrs_out[(size_t)(rbase + g4 * 4 + i) * 256 + 128 + cf * 16 + r16] = f2bf(acc2[cf][i]);
        } else {
            f32x4 acc2[8];
            ldsA_gemm(T0, p.wnp0t, acc2, r16, g4);
            tile_store(T1, acc2, p.nb0, r16, g4);
            ldsA_gemm(T1, p.wnp1t, acc2, r16, g4);
            tile_store(T0, acc2, p.nb1, r16, g4);
            if (g4 < 3) {
                int grow = rbase + r16;
                int b = grow >> 11, n = grow & 2047;
                if (n < N_P) {
                    float s = p.nb2[g4];
                    for (int k = 0; k < NF; ++k)
                        s += bf2f(T0[r16 * NF + SWZ(r16, k)]) * p.np_W2[k * 3 + g4];
                    s = fminf(fmaxf(s, -100.f), 100.f);
                    p.out[((size_t)b * N_P + n) * 3 + g4] =
                        s + p.state[(((size_t)b * 4 + 3) * N_ALL + n) * 3 + g4];
                }
            }
        }
    }
}

__global__ __launch_bounds__(256) void step_m(StepP p)
{
    __shared__ float aggL[32][NF];
    __shared__ u16 tw[2][2][16 * NF];
    u16* twbase = &tw[0][0][0];

    step_body<0>(p, aggL, twbase, p.ZrsA, p.penc, p.effX, p.ZrsB);
    grid_bar(p.bar, 128);
    step_body<0>(p, aggL, twbase, p.ZrsB, p.effX, p.effY, p.ZrsA);
    grid_bar(p.bar, 256);
    step_body<1>(p, aggL, twbase, p.ZrsA, p.effY, nullptr, nullptr);
}

// ---------------------------------------------------------------------------
extern "C" void kernel_launch(void* const* d_in, const int* in_sizes, int n_in,
                              void* d_out, int out_size, void* d_ws, size_t ws_size,
                              hipStream_t stream) {
    (void)in_sizes; (void)n_in; (void)out_size; (void)ws_size;
    const float* state      = (const float*)d_in[0];
    const float* attrs      = (const float*)d_in[1];
    const float* Rr         = (const float*)d_in[2];
    const float* Rs         = (const float*)d_in[3];
    const float* p_instance = (const float*)d_in[4];
    const float* action     = (const float*)d_in[5];
    const float* den        = (const float*)d_in[6];
    const float* phys       = (const float*)d_in[7];
    const float* pe_W0 = (const float*)d_in[8];  const float* pe_b0 = (const float*)d_in[9];
    const float* pe_W1 = (const float*)d_in[10]; const float* pe_b1 = (const float*)d_in[11];
    const float* pe_W2 = (const float*)d_in[12]; const float* pe_b2 = (const float*)d_in[13];
    const float* re_W0 = (const float*)d_in[14]; const float* re_b0 = (const float*)d_in[15];
    const float* re_W1 = (const float*)d_in[16]; const float* re_b1 = (const float*)d_in[17];
    const float* re_W2 = (const float*)d_in[18]; const float* re_b2 = (const float*)d_in[19];
    const float* pp_W  = (const float*)d_in[20]; const float* pp_b  = (const float*)d_in[21];
    const float* rp_W  = (const float*)d_in[22]; const float* rp_b  = (const float*)d_in[23];
    const float* np_W0 = (const float*)d_in[24]; const float* np_b0 = (const float*)d_in[25];
    const float* np_W1 = (const float*)d_in[26]; const float* np_b1 = (const float*)d_in[27];
    const float* np_W2 = (const float*)d_in[28]; const float* np_b2 = (const float*)d_in[29];

    char* base = (char*)d_ws;
    size_t off = 0;
    auto alloc = [&](size_t bytes) -> void* {
        off = (off + 255) & ~(size_t)255;
        void* p = base + off; off += bytes; return p;
    };
    const int RN = B * N_ALL;    // 4096
    const int RE = B * N_REL;    // 16384
    int*   rr      = (int*)alloc(RE * 4);
    int*   rs      = (int*)alloc(RE * 4);
    int*   cnt     = (int*)alloc(RN * 4);
    int*   bar     = (int*)alloc(256);
    int2*  buckets = (int2*)alloc((size_t)RN * DEG_CAP * 8);
    u16*   P       = (u16*)alloc((size_t)RN * 32 * 2);
    u16*   penc    = (u16*)alloc((size_t)RN * NF * 2);
    u16*   relencW = (u16*)alloc((size_t)RE * NF * 2);
    float* Zp      = (float*)alloc((size_t)RN * NF * 4);
    u16*   ZrsA    = (u16*)alloc((size_t)RN * 256 * 2);
    u16*   ZrsB    = (u16*)alloc((size_t)RN * 256 * 2);
    u16*   effX    = (u16*)alloc((size_t)RN * NF * 2);
    u16*   effY    = (u16*)alloc((size_t)RN * NF * 2);

    WtCvt d;
    const float* srcs[NWT] = {pe_W0, pe_W1, pe_W2, re_W0, re_W1, re_W2,
                              rp_W, rp_W + 128 * NF, rp_W + 256 * NF,
                              pp_W, pp_W + 128 * NF, np_W0, np_W1};
    const int Ks[NWT]  = {19, 128, 128, 56, 128, 128, 128, 128, 128, 128, 128, 128, 128};
    const int Kps[NWT] = {32, 128, 128, 64, 128, 128, 128, 128, 128, 128, 128, 128, 128};
    d.cum[0] = 0;
    for (int i = 0; i < NWT; ++i) {
        d.src[i] = srcs[i]; d.K[i] = Ks[i]; d.Kpad[i] = Kps[i];
        d.cum[i + 1] = d.cum[i] + NF * Kps[i];
    }
    int wt_total = d.cum[NWT];
    u16* wt = (u16*)alloc((size_t)wt_total * 2);
    const u16 *wpe0 = wt + d.cum[0], *wpe1 = wt + d.cum[1], *wpe2 = wt + d.cum[2];
    const u16 *wre0 = wt + d.cum[3], *wre1 = wt + d.cum[4], *wre2 = wt + d.cum[5];
    const u16 *wrp0t = wt + d.cum[6], *wrp1t = wt + d.cum[7], *wrp2t = wt + d.cum[8];
    const u16 *wpp0t = wt + d.cum[9], *wpp1t = wt + d.cum[10];
    const u16 *wnp0t = wt + d.cum[11], *wnp1t = wt + d.cum[12];

    scan_h0<<<H0_TOTAL, 256, 0, stream>>>(Rr, Rs, rr, rs, d, wt, wt_total,
                                          state, attrs, action, den, phys, P);
    scan_stripe<1024><<<8192, 256, 0, stream>>>(Rr, Rs, rr, rs, cnt, bar);
    scan_stripe<1536><<<8192 + 16, 256, 0, stream>>>(Rr, Rs, rr, rs, cnt, bar);

    enc2<<<ENC_TOTAL, 256, 0, stream>>>(P, attrs, p_instance, rr, rs,
        wpe0, wpe1, wpe2, pe_b0, pe_b1, pe_b2,
        wre0, wre1, wre2, re_b0, re_b1, re_b2,
        rp_b, wrp0t, wpp0t, wrp1t, wrp2t,
        penc, relencW, Zp, ZrsA, cnt, buckets);

    StepP sp;
    sp.cnt = cnt; sp.buckets = buckets;
    sp.relencW = relencW; sp.Zp = Zp; sp.pp_b = pp_b;
    sp.wpp1t = wpp1t; sp.wrp1t = wrp1t; sp.wrp2t = wrp2t;
    sp.wnp0t = wnp0t; sp.wnp1t = wnp1t; sp.nb0 = np_b0; sp.nb1 = np_b1;
    sp.np_W2 = np_W2; sp.nb2 = np_b2;
    sp.state = state; sp.out = (float*)d_out;
    sp.penc = penc; sp.effX = effX; sp.effY = effY; sp.ZrsA = ZrsA; sp.ZrsB = ZrsB;
    sp.bar = bar;

    step_m<<<128, 256, 0, stream>>>(sp);
}

// Round 15
// 113.231 us; speedup vs baseline: 1.4715x; 1.4715x over previous
//
#include <hip/hip_runtime.h>

#define B 2
#define N_P 2000
#define N_ALL 2048
#define N_REL 8192
#define N_INST 8
#define NF 128
#define DEG_CAP 64

typedef unsigned short u16;
typedef __attribute__((ext_vector_type(8))) short bf16x8;
typedef __attribute__((ext_vector_type(4))) float f32x4;

__device__ __forceinline__ u16 f2bf(float f) {
    union { float f; unsigned u; } v; v.f = f;
    unsigned r = v.u + 0x7FFFu + ((v.u >> 16) & 1u);
    return (u16)(r >> 16);
}
__device__ __forceinline__ float bf2f(u16 h) {
    union { unsigned u; float f; } v; v.u = ((unsigned)h) << 16; return v.f;
}

#define MFMA16(a, b, c) __builtin_amdgcn_mfma_f32_16x16x32_bf16((a), (b), (c), 0, 0, 0)
#define SWZ(row, col) ((col) ^ (((row) & 7) << 3))

#define NWT 13
struct WtCvt {
    const float* src[NWT];
    int K[NWT];
    int Kpad[NWT];
    int cum[NWT + 1];
};

// ---------------------------------------------------------------------------
// D1: scan_q0: [0,8192) rows' first 512 floats unconditional;
//     [8192,8944) weight convert; [8944,8960) p_inputs build.
// ---------------------------------------------------------------------------
#define Q0_SCAN_BLKS 8192
#define Q0_CVT_BLKS  752
#define Q0_PIN_BLKS  16
#define Q0_TOTAL (Q0_SCAN_BLKS + Q0_CVT_BLKS + Q0_PIN_BLKS)

__global__ __launch_bounds__(256) void scan_q0(
    const float* __restrict__ Rr, const float* __restrict__ Rs,
    int* __restrict__ rr, int* __restrict__ rs,
    WtCvt d, u16* __restrict__ wt, int wt_total,
    const float* __restrict__ state, const float* __restrict__ attrs,
    const float* __restrict__ action, const float* __restrict__ den,
    const float* __restrict__ phys, u16* __restrict__ P)
{
    int blk = blockIdx.x;
    if (blk < Q0_SCAN_BLKS) {
        int lane = threadIdx.x & 63;
        int r = blk * 4 + (threadIdx.x >> 6);          // 0..32767
        const float* base = (r < 16384 ? Rr + (size_t)r * N_ALL
                                       : Rs + (size_t)(r - 16384) * N_ALL);
        const f32x4* s = reinterpret_cast<const f32x4*>(base + lane * 8);
        f32x4 v0 = s[0], v1 = s[1];
        int f = -1;
        int bi = lane * 8;
        #pragma unroll
        for (int j = 0; j < 4; ++j) {
            if (v0[j] != 0.f) f = bi + j;
            if (v1[j] != 0.f) f = bi + 4 + j;
        }
        #pragma unroll
        for (int off = 32; off; off >>= 1) f = max(f, __shfl_xor(f, off));
        if (lane == 0) {
            int* outp = (r < 16384) ? rr : rs;
            outp[r & 16383] = f;
        }
        return;
    }
    blk -= Q0_SCAN_BLKS;
    if (blk < Q0_CVT_BLKS) {
        int t = blk * 256 + threadIdx.x;
        if (t >= wt_total) return;
        int m = 0;
        while (t >= d.cum[m + 1]) m++;
        int loc = t - d.cum[m];
        int Kp = d.Kpad[m];
        int c = loc / Kp, k = loc - c * Kp;
        float v = (k < d.K[m]) ? d.src[m][(size_t)k * NF + c] : 0.f;
        wt[t] = f2bf(v);
        return;
    }
    blk -= Q0_CVT_BLKS;
    {
        int t = blk * 256 + threadIdx.x;
        if (t >= B * N_ALL) return;
        int b = t >> 11, n = t & 2047;
        float o[19];
        o[0] = attrs[t * 2]; o[1] = attrs[t * 2 + 1];
        #pragma unroll
        for (int h = 0; h < 3; ++h)
            #pragma unroll
            for (int c = 0; c < 3; ++c)
                o[2 + h * 3 + c] = state[(((size_t)b * 4 + h + 1) * N_ALL + n) * 3 + c]
                                 - state[(((size_t)b * 4 + h)     * N_ALL + n) * 3 + c];
        #pragma unroll
        for (int c = 0; c < 3; ++c)
            o[11 + c] = state[(((size_t)b * 4 + 3) * N_ALL + n) * 3 + c];
        o[14] = (n < N_P) ? phys[b] : 0.f;
        #pragma unroll
        for (int c = 0; c < 3; ++c) o[15 + c] = action[t * 3 + c];
        o[18] = (n < N_P) ? den[b] : 0.f;
        u16* dst = P + (size_t)t * 32;
        #pragma unroll
        for (int k = 0; k < 19; ++k) dst[k] = f2bf(o[k]);
        #pragma unroll
        for (int k = 19; k < 32; ++k) dst[k] = 0;
    }
}

// ---------------------------------------------------------------------------
// Conditional 512-float stripe scans (START = 512/1024/1536). Blocks >= 8192
// zero the degree counters (only launched that wide on the last stripe).
// ---------------------------------------------------------------------------
template<int START>
__global__ __launch_bounds__(256) void scan_stripe(
    const float* __restrict__ Rr, const float* __restrict__ Rs,
    int* __restrict__ rr, int* __restrict__ rs, int* __restrict__ cnt)
{
    if (blockIdx.x >= 8192) {
        int t = (blockIdx.x - 8192) * 256 + threadIdx.x;
        if (t < B * N_ALL) cnt[t] = 0;
        return;
    }
    int lane = threadIdx.x & 63;
    int r = blockIdx.x * 4 + (threadIdx.x >> 6);
    int* outp = (r < 16384) ? rr : rs;
    int e = r & 16383;
    if (outp[e] >= 0) return;
    const float* base = ((r < 16384) ? Rr + (size_t)r * N_ALL
                                     : Rs + (size_t)(r - 16384) * N_ALL) + START;
    const f32x4* s = reinterpret_cast<const f32x4*>(base + lane * 8);
    f32x4 v0 = s[0], v1 = s[1];
    int f = -1;
    int bi = START + lane * 8;
    #pragma unroll
    for (int j = 0; j < 4; ++j) {
        if (v0[j] != 0.f) f = bi + j;
        if (v1[j] != 0.f) f = bi + 4 + j;
    }
    #pragma unroll
    for (int off = 32; off; off >>= 1) f = max(f, __shfl_xor(f, off));
    if (lane == 0) outp[e] = f;
}

// ---------------------------------------------------------------------------
// Layer helpers (wave = 16 rows). ldsA_gemm: full 128 cols; ldsA_gemm4: 64-col
// half starting at colbase.
// ---------------------------------------------------------------------------
__device__ __forceinline__ void ldsA_gemm(const u16* T, const u16* __restrict__ wtm,
                                          f32x4 acc[8], int r16, int g4)
{
    #pragma unroll
    for (int cf = 0; cf < 8; ++cf) acc[cf] = (f32x4){0.f, 0.f, 0.f, 0.f};
    #pragma unroll
    for (int kf = 0; kf < 4; ++kf) {
        int kcol = kf * 32 + g4 * 8;
        bf16x8 a = *reinterpret_cast<const bf16x8*>(&T[r16 * NF + SWZ(r16, kcol)]);
        #pragma unroll
        for (int cf = 0; cf < 8; ++cf) {
            bf16x8 bv = *reinterpret_cast<const bf16x8*>(wtm + (size_t)(cf * 16 + r16) * NF + kcol);
            acc[cf] = MFMA16(a, bv, acc[cf]);
        }
    }
}
__device__ __forceinline__ void ldsA_gemm4(const u16* T, const u16* __restrict__ wtm,
                                           int colbase, f32x4 acc[4], int r16, int g4)
{
    #pragma unroll
    for (int cf = 0; cf < 4; ++cf) acc[cf] = (f32x4){0.f, 0.f, 0.f, 0.f};
    #pragma unroll
    for (int kf = 0; kf < 4; ++kf) {
        int kcol = kf * 32 + g4 * 8;
        bf16x8 a = *reinterpret_cast<const bf16x8*>(&T[r16 * NF + SWZ(r16, kcol)]);
        #pragma unroll
        for (int cf = 0; cf < 4; ++cf) {
            bf16x8 bv = *reinterpret_cast<const bf16x8*>(wtm + (size_t)(colbase + cf * 16 + r16) * NF + kcol);
            acc[cf] = MFMA16(a, bv, acc[cf]);
        }
    }
}
__device__ __forceinline__ void tile_store(u16* T, f32x4 acc[8], const float* __restrict__ bias,
                                           int r16, int g4)
{
    #pragma unroll
    for (int cf = 0; cf < 8; ++cf) {
        float bb = bias[cf * 16 + r16];
        #pragma unroll
        for (int i = 0; i < 4; ++i) {
            int row = g4 * 4 + i, col = cf * 16 + r16;
            T[row * NF + SWZ(row, col)] = f2bf(fmaxf(acc[cf][i] + bb, 0.f));
        }
    }
}

// ---------------------------------------------------------------------------
// ENC2 (128-thread blocks, 32 rows each for better occupancy):
//   [0,512): relation encoder (3 layers + fused @rp_W0+rp_b)
//   [512,640): particle encoder + Zp + Zrs0
//   [640,648): bucket fill
// ---------------------------------------------------------------------------
#define ENC_REL_BLKS 512
#define ENC_PART_BLKS 128
#define ENC_FILL_BLKS 8
#define ENC_TOTAL (ENC_REL_BLKS + ENC_PART_BLKS + ENC_FILL_BLKS)

__global__ __launch_bounds__(128) void enc2(
    const u16* __restrict__ P, const float* __restrict__ attrs,
    const float* __restrict__ p_inst,
    const int* __restrict__ rr, const int* __restrict__ rs,
    const u16* __restrict__ wpe0, const u16* __restrict__ wpe1, const u16* __restrict__ wpe2,
    const float* __restrict__ pb0, const float* __restrict__ pb1, const float* __restrict__ pb2,
    const u16* __restrict__ wre0, const u16* __restrict__ wre1, const u16* __restrict__ wre2,
    const float* __restrict__ rb0, const float* __restrict__ rb1, const float* __restrict__ rb2,
    const float* __restrict__ rp_b, const u16* __restrict__ wrp0t,
    const u16* __restrict__ wpp0t, const u16* __restrict__ wrp1t, const u16* __restrict__ wrp2t,
    u16* __restrict__ penc, u16* __restrict__ relencW,
    float* __restrict__ Zp, u16* __restrict__ Zrs0,
    int* __restrict__ cnt, int2* __restrict__ buckets)
{
    __shared__ u16 ri[32 * 64];            // 4 KB
    __shared__ u16 tw[2][2][16 * NF];      // 16 KB
    int tid = threadIdx.x;
    int blk = blockIdx.x;

    if (blk >= ENC_REL_BLKS + ENC_PART_BLKS) {
        int t = (blk - ENC_REL_BLKS - ENC_PART_BLKS) * 128 + tid;
        for (int e = t; e < B * N_REL; e += ENC_FILL_BLKS * 128) {
            int n = ((e >> 13) << 11) + rr[e];
            int pos = atomicAdd(&cnt[n], 1);
            if (pos < DEG_CAP) {
                int2 v; v.x = e; v.y = ((e >> 13) << 11) + rs[e];
                buckets[(size_t)n * DEG_CAP + pos] = v;
            }
        }
        return;
    }

    int w = tid >> 6, lane = tid & 63;
    int r16 = lane & 15, g4 = lane >> 4;
    u16* T0 = tw[w][0];
    u16* T1 = tw[w][1];
    f32x4 acc[8];

    if (blk < ENC_REL_BLKS) {
        {
            int row = tid >> 2;                  // 0..31
            int q = tid & 3;
            int grow = blk * 32 + row;
            int b = grow >> 13;
            int ir = rr[grow], is_ = rs[grow];
            const u16* pr = P + ((size_t)(b << 11) + ir) * 32;
            const u16* ps = P + ((size_t)(b << 11) + is_) * 32;
            float gd = 0.f;
            if (q == 2) {
                #pragma unroll
                for (int k = 0; k < N_INST; ++k) {
                    float gr = (ir < N_P) ? p_inst[((size_t)b * N_P + ir) * N_INST + k] : 0.f;
                    float gs = (is_ < N_P) ? p_inst[((size_t)b * N_P + is_) * N_INST + k] : 0.f;
                    gd += fabsf(gr - gs);
                }
            }
            #pragma unroll
            for (int j = 0; j < 16; ++j) {
                int c = q * 16 + j;
                u16 hv;
                if (c < 19)       hv = pr[c];
                else if (c < 38)  hv = ps[c - 19];
                else if (c < 40)  hv = f2bf(attrs[((size_t)(b << 11) + ir) * 2 + (c - 38)]);
                else if (c < 42)  hv = f2bf(attrs[((size_t)(b << 11) + is_) * 2 + (c - 40)]);
                else if (c == 42) hv = f2bf(gd);
                else if (c < 55)  hv = f2bf(bf2f(pr[c - 41]) - bf2f(ps[c - 41]));
                else if (c == 55) hv = f2bf(bf2f(pr[18]) - bf2f(ps[18]));
                else              hv = 0;
                ri[row * 64 + SWZ(row, c)] = hv;
            }
        }
        __syncthreads();
        int rbase = blk * 32 + w * 16;
        #pragma unroll
        for (int cf = 0; cf < 8; ++cf) acc[cf] = (f32x4){0.f, 0.f, 0.f, 0.f};
        #pragma unroll
        for (int kf = 0; kf < 2; ++kf) {
            int kcol = kf * 32 + g4 * 8;
            int lr = w * 16 + r16;
            bf16x8 a = *reinterpret_cast<const bf16x8*>(&ri[lr * 64 + SWZ(lr, kcol)]);
            #pragma unroll
            for (int cf = 0; cf < 8; ++cf) {
                bf16x8 bv = *reinterpret_cast<const bf16x8*>(wre0 + (size_t)(cf * 16 + r16) * 64 + kcol);
                acc[cf] = MFMA16(a, bv, acc[cf]);
            }
        }
        tile_store(T0, acc, rb0, r16, g4);
        ldsA_gemm(T0, wre1, acc, r16, g4);
        tile_store(T1, acc, rb1, r16, g4);
        ldsA_gemm(T1, wre2, acc, r16, g4);
        tile_store(T0, acc, rb2, r16, g4);
        ldsA_gemm(T0, wrp0t, acc, r16, g4);
        #pragma unroll
        for (int cf = 0; cf < 8; ++cf) {
            float bb = rp_b[cf * 16 + r16];
            #pragma unroll
            for (int i = 0; i < 4; ++i) {
                int grow = rbase + g4 * 4 + i;
                relencW[(size_t)grow * NF + cf * 16 + r16] = f2bf(acc[cf][i] + bb);
            }
        }
        return;
    }

    int blk2 = blk - ENC_REL_BLKS;
    int rbase = blk2 * 32 + w * 16;
    #pragma unroll
    for (int cf = 0; cf < 8; ++cf) acc[cf] = (f32x4){0.f, 0.f, 0.f, 0.f};
    {
        int kcol = g4 * 8;
        bf16x8 a = *reinterpret_cast<const bf16x8*>(P + (size_t)(rbase + r16) * 32 + kcol);
        #pragma unroll
        for (int cf = 0; cf < 8; ++cf) {
            bf16x8 bv = *reinterpret_cast<const bf16x8*>(wpe0 + (size_t)(cf * 16 + r16) * 32 + kcol);
            acc[cf] = MFMA16(a, bv, acc[cf]);
        }
    }
    tile_store(T0, acc, pb0, r16, g4);
    ldsA_gemm(T0, wpe1, acc, r16, g4);
    tile_store(T1, acc, pb1, r16, g4);
    ldsA_gemm(T1, wpe2, acc, r16, g4);
    tile_store(T0, acc, pb2, r16, g4);
    #pragma unroll
    for (int cf = 0; cf < 8; ++cf)
        #pragma unroll
        for (int i = 0; i < 4; ++i) {
            int row = g4 * 4 + i, col = cf * 16 + r16;
            penc[(size_t)(rbase + row) * NF + col] = T0[row * NF + SWZ(row, col)];
        }
    ldsA_gemm(T0, wpp0t, acc, r16, g4);
    #pragma unroll
    for (int cf = 0; cf < 8; ++cf)
        #pragma unroll
        for (int i = 0; i < 4; ++i)
            Zp[(size_t)(rbase + g4 * 4 + i) * NF + cf * 16 + r16] = acc[cf][i];
    ldsA_gemm(T0, wrp1t, acc, r16, g4);
    #pragma unroll
    for (int cf = 0; cf < 8; ++cf)
        #pragma unroll
        for (int i = 0; i < 4; ++i)
            Zrs0[(size_t)(rbase + g4 * 4 + i) * 256 + cf * 16 + r16] = f2bf(acc[cf][i]);
    ldsA_gemm(T0, wrp2t, acc, r16, g4);
    #pragma unroll
    for (int cf = 0; cf < 8; ++cf)
        #pragma unroll
        for (int i = 0; i < 4; ++i)
            Zrs0[(size_t)(rbase + g4 * 4 + i) * 256 + 128 + cf * 16 + r16] = f2bf(acc[cf][i]);
}

// ---------------------------------------------------------------------------
// STEP_C (128-thread blocks, 16 nodes each, 256 blocks):
//   phase 1: 8 thr/node x 16 cols, batched 4-edge prefetch.
//   phase 2: both waves GEMM (wave w = 64-col half), shared 16-row tiles.
// ---------------------------------------------------------------------------
template<int LAST>
__global__ __launch_bounds__(128) void step_c(
    const int* __restrict__ cnt, const int2* __restrict__ buckets,
    const u16* __restrict__ relencW, const u16* __restrict__ Zrs,
    const float* __restrict__ Zp, const float* __restrict__ pp_b,
    const u16* __restrict__ eff_prev,
    const u16* __restrict__ wpp1t, const u16* __restrict__ wrp1t, const u16* __restrict__ wrp2t,
    u16* __restrict__ eff_out, u16* __restrict__ Zrs_out,
    const u16* __restrict__ wnp0t, const u16* __restrict__ wnp1t,
    const float* __restrict__ nb0, const float* __restrict__ nb1,
    const float* __restrict__ np_W2, const float* __restrict__ nb2,
    const float* __restrict__ state, float* __restrict__ out)
{
    __shared__ float aggL[16][NF];        // 8 KB
    __shared__ u16 T0s[16 * NF];          // 4 KB
    __shared__ u16 T1s[16 * NF];          // 4 KB
    int tid = threadIdx.x;
    int w = tid >> 6, lane = tid & 63;
    int r16 = lane & 15, g4 = lane >> 4;
    int nbase = blockIdx.x * 16;

    // ---- phase 1: bucket aggregation ----
    {
        int ln = tid >> 3;                 // 0..15
        int q  = tid & 7;                  // 16-col group
        int n  = nbase + ln;
        const u16* zrp = Zrs + (size_t)n * 256 + q * 16;
        bf16x8 z0 = *reinterpret_cast<const bf16x8*>(zrp);
        bf16x8 z1 = *reinterpret_cast<const bf16x8*>(zrp + 8);
        float zr[16];
        #pragma unroll
        for (int j = 0; j < 8; ++j) { zr[j] = bf2f((u16)z0[j]); zr[8 + j] = bf2f((u16)z1[j]); }
        float a16[16];
        #pragma unroll
        for (int j = 0; j < 16; ++j) a16[j] = 0.f;
        int k1 = min(cnt[n], DEG_CAP);
        const int2* eb_base = buckets + (size_t)n * DEG_CAP;
        for (int k = 0; k < k1; k += 4) {
            int m = k1 - k;
            int2 eb[4];
            #pragma unroll
            for (int t = 0; t < 4; ++t) if (t < m) eb[t] = eb_base[k + t];
            #pragma unroll
            for (int t = 0; t < 4; ++t) if (t < m) {
                const u16* rwp = relencW + (size_t)eb[t].x * NF + q * 16;
                const u16* zsp = Zrs + (size_t)eb[t].y * 256 + 128 + q * 16;
                bf16x8 rw0 = *reinterpret_cast<const bf16x8*>(rwp);
                bf16x8 rw1 = *reinterpret_cast<const bf16x8*>(rwp + 8);
                bf16x8 zs0 = *reinterpret_cast<const bf16x8*>(zsp);
                bf16x8 zs1 = *reinterpret_cast<const bf16x8*>(zsp + 8);
                #pragma unroll
                for (int j = 0; j < 8; ++j) {
                    a16[j]     += fmaxf(bf2f((u16)rw0[j]) + zr[j]     + bf2f((u16)zs0[j]), 0.f);
                    a16[8 + j] += fmaxf(bf2f((u16)rw1[j]) + zr[8 + j] + bf2f((u16)zs1[j]), 0.f);
                }
            }
        }
        int c0 = q * 16;
        int pc0 = c0 ^ ((ln & 7) << 3);
        int pc1 = (c0 + 8) ^ ((ln & 7) << 3);
        #pragma unroll
        for (int j = 0; j < 8; ++j) {
            aggL[ln][pc0 + j] = a16[j];
            aggL[ln][pc1 + j] = a16[8 + j];
        }
    }
    __syncthreads();

    // ---- phase 2: GEMM aggL @ pp_W1, wave w owns cols [w*64, w*64+64) ----
    int cb = w * 64;
    f32x4 acc[4];
    #pragma unroll
    for (int cf = 0; cf < 4; ++cf) acc[cf] = (f32x4){0.f, 0.f, 0.f, 0.f};
    #pragma unroll
    for (int kf = 0; kf < 4; ++kf) {
        int kcol = kf * 32 + g4 * 8;
        int pc = kcol ^ ((r16 & 7) << 3);
        float4 lo = *reinterpret_cast<const float4*>(&aggL[r16][pc]);
        float4 hi = *reinterpret_cast<const float4*>(&aggL[r16][pc + 4]);
        bf16x8 a;
        a[0] = (short)f2bf(lo.x); a[1] = (short)f2bf(lo.y);
        a[2] = (short)f2bf(lo.z); a[3] = (short)f2bf(lo.w);
        a[4] = (short)f2bf(hi.x); a[5] = (short)f2bf(hi.y);
        a[6] = (short)f2bf(hi.z); a[7] = (short)f2bf(hi.w);
        #pragma unroll
        for (int cf = 0; cf < 4; ++cf) {
            bf16x8 bv = *reinterpret_cast<const bf16x8*>(wpp1t + (size_t)(cb + cf * 16 + r16) * NF + kcol);
            acc[cf] = MFMA16(a, bv, acc[cf]);
        }
    }
    #pragma unroll
    for (int cf = 0; cf < 4; ++cf) {
        int col = cb + cf * 16 + r16;
        float bb = pp_b[col];
        #pragma unroll
        for (int i = 0; i < 4; ++i) {
            int trow = g4 * 4 + i;
            int grow = nbase + trow;
            float v = acc[cf][i] + bb + Zp[(size_t)grow * NF + col]
                    + bf2f(eff_prev[(size_t)grow * NF + col]);
            u16 hv = f2bf(fmaxf(v, 0.f));
            T0s[trow * NF + SWZ(trow, col)] = hv;
            if (!LAST) eff_out[(size_t)grow * NF + col] = hv;
        }
    }
    __syncthreads();     // T0s complete (both col halves)

    if (!LAST) {
        f32x4 a2[4];
        ldsA_gemm4(T0s, wrp1t, cb, a2, r16, g4);
        #pragma unroll
        for (int cf = 0; cf < 4; ++cf)
            #pragma unroll
            for (int i = 0; i < 4; ++i)
                Zrs_out[(size_t)(nbase + g4 * 4 + i) * 256 + cb + cf * 16 + r16] = f2bf(a2[cf][i]);
        ldsA_gemm4(T0s, wrp2t, cb, a2, r16, g4);
        #pragma unroll
        for (int cf = 0; cf < 4; ++cf)
            #pragma unroll
            for (int i = 0; i < 4; ++i)
                Zrs_out[(size_t)(nbase + g4 * 4 + i) * 256 + 128 + cb + cf * 16 + r16] = f2bf(a2[cf][i]);
    } else {
        // np0: both waves (col halves) -> T1s
        f32x4 a2[4];
        ldsA_gemm4(T0s, wnp0t, cb, a2, r16, g4);
        #pragma unroll
        for (int cf = 0; cf < 4; ++cf) {
            float bb = nb0[cb + cf * 16 + r16];
            #pragma unroll
            for (int i = 0; i < 4; ++i) {
                int row = g4 * 4 + i, col = cb + cf * 16 + r16;
                T1s[row * NF + SWZ(row, col)] = f2bf(fmaxf(a2[cf][i] + bb, 0.f));
            }
        }
        __syncthreads();
        // np1 -> T0s
        ldsA_gemm4(T1s, wnp1t, cb, a2, r16, g4);
        #pragma unroll
        for (int cf = 0; cf < 4; ++cf) {
            float bb = nb1[cb + cf * 16 + r16];
            #pragma unroll
            for (int i = 0; i < 4; ++i) {
                int row = g4 * 4 + i, col = cb + cf * 16 + r16;
                T0s[row * NF + SWZ(row, col)] = f2bf(fmaxf(a2[cf][i] + bb, 0.f));
            }
        }
        __syncthreads();
        // head: wave 0, 3 cols x 16 rows
        if (w == 0 && g4 < 3) {
            int grow = nbase + r16;
            int b = grow >> 11, n = grow & 2047;
            if (n < N_P) {
                float s = nb2[g4];
                for (int k = 0; k < NF; ++k)
                    s += bf2f(T0s[r16 * NF + SWZ(r16, k)]) * np_W2[k * 3 + g4];
                s = fminf(fmaxf(s, -100.f), 100.f);
                out[((size_t)b * N_P + n) * 3 + g4] =
                    s + state[(((size_t)b * 4 + 3) * N_ALL + n) * 3 + g4];
            }
        }
    }
}

// ---------------------------------------------------------------------------
extern "C" void kernel_launch(void* const* d_in, const int* in_sizes, int n_in,
                              void* d_out, int out_size, void* d_ws, size_t ws_size,
                              hipStream_t stream) {
    (void)in_sizes; (void)n_in; (void)out_size; (void)ws_size;
    const float* state      = (const float*)d_in[0];
    const float* attrs      = (const float*)d_in[1];
    const float* Rr         = (const float*)d_in[2];
    const float* Rs         = (const float*)d_in[3];
    const float* p_instance = (const float*)d_in[4];
    const float* action     = (const float*)d_in[5];
    const float* den        = (const float*)d_in[6];
    const float* phys       = (const float*)d_in[7];
    const float* pe_W0 = (const float*)d_in[8];  const float* pe_b0 = (const float*)d_in[9];
    const float* pe_W1 = (const float*)d_in[10]; const float* pe_b1 = (const float*)d_in[11];
    const float* pe_W2 = (const float*)d_in[12]; const float* pe_b2 = (const float*)d_in[13];
    const float* re_W0 = (const float*)d_in[14]; const float* re_b0 = (const float*)d_in[15];
    const float* re_W1 = (const float*)d_in[16]; const float* re_b1 = (const float*)d_in[17];
    const float* re_W2 = (const float*)d_in[18]; const float* re_b2 = (const float*)d_in[19];
    const float* pp_W  = (const float*)d_in[20]; const float* pp_b  = (const float*)d_in[21];
    const float* rp_W  = (const float*)d_in[22]; const float* rp_b  = (const float*)d_in[23];
    const float* np_W0 = (const float*)d_in[24]; const float* np_b0 = (const float*)d_in[25];
    const float* np_W1 = (const float*)d_in[26]; const float* np_b1 = (const float*)d_in[27];
    const float* np_W2 = (const float*)d_in[28]; const float* np_b2 = (const float*)d_in[29];

    char* base = (char*)d_ws;
    size_t off = 0;
    auto alloc = [&](size_t bytes) -> void* {
        off = (off + 255) & ~(size_t)255;
        void* p = base + off; off += bytes; return p;
    };
    const int RN = B * N_ALL;    // 4096
    const int RE = B * N_REL;    // 16384
    int*   rr      = (int*)alloc(RE * 4);
    int*   rs      = (int*)alloc(RE * 4);
    int*   cnt     = (int*)alloc(RN * 4);
    int2*  buckets = (int2*)alloc((size_t)RN * DEG_CAP * 8);
    u16*   P       = (u16*)alloc((size_t)RN * 32 * 2);
    u16*   penc    = (u16*)alloc((size_t)RN * NF * 2);
    u16*   relencW = (u16*)alloc((size_t)RE * NF * 2);
    float* Zp      = (float*)alloc((size_t)RN * NF * 4);
    u16*   ZrsA    = (u16*)alloc((size_t)RN * 256 * 2);
    u16*   ZrsB    = (u16*)alloc((size_t)RN * 256 * 2);
    u16*   effX    = (u16*)alloc((size_t)RN * NF * 2);
    u16*   effY    = (u16*)alloc((size_t)RN * NF * 2);

    WtCvt d;
    const float* srcs[NWT] = {pe_W0, pe_W1, pe_W2, re_W0, re_W1, re_W2,
                              rp_W, rp_W + 128 * NF, rp_W + 256 * NF,
                              pp_W, pp_W + 128 * NF, np_W0, np_W1};
    const int Ks[NWT]  = {19, 128, 128, 56, 128, 128, 128, 128, 128, 128, 128, 128, 128};
    const int Kps[NWT] = {32, 128, 128, 64, 128, 128, 128, 128, 128, 128, 128, 128, 128};
    d.cum[0] = 0;
    for (int i = 0; i < NWT; ++i) {
        d.src[i] = srcs[i]; d.K[i] = Ks[i]; d.Kpad[i] = Kps[i];
        d.cum[i + 1] = d.cum[i] + NF * Kps[i];
    }
    int wt_total = d.cum[NWT];
    u16* wt = (u16*)alloc((size_t)wt_total * 2);
    const u16 *wpe0 = wt + d.cum[0], *wpe1 = wt + d.cum[1], *wpe2 = wt + d.cum[2];
    const u16 *wre0 = wt + d.cum[3], *wre1 = wt + d.cum[4], *wre2 = wt + d.cum[5];
    const u16 *wrp0t = wt + d.cum[6], *wrp1t = wt + d.cum[7], *wrp2t = wt + d.cum[8];
    const u16 *wpp0t = wt + d.cum[9], *wpp1t = wt + d.cum[10];
    const u16 *wnp0t = wt + d.cum[11], *wnp1t = wt + d.cum[12];

    scan_q0<<<Q0_TOTAL, 256, 0, stream>>>(Rr, Rs, rr, rs, d, wt, wt_total,
                                          state, attrs, action, den, phys, P);
    scan_stripe<512><<<8192, 256, 0, stream>>>(Rr, Rs, rr, rs, cnt);
    scan_stripe<1024><<<8192, 256, 0, stream>>>(Rr, Rs, rr, rs, cnt);
    scan_stripe<1536><<<8192 + 16, 256, 0, stream>>>(Rr, Rs, rr, rs, cnt);

    enc2<<<ENC_TOTAL, 128, 0, stream>>>(P, attrs, p_instance, rr, rs,
        wpe0, wpe1, wpe2, pe_b0, pe_b1, pe_b2,
        wre0, wre1, wre2, re_b0, re_b1, re_b2,
        rp_b, wrp0t, wpp0t, wrp1t, wrp2t,
        penc, relencW, Zp, ZrsA, cnt, buckets);

    const u16* Zcur = ZrsA;
    const u16* effp = penc;
    u16* Znext[2] = {ZrsB, ZrsA};
    u16* effn[2]  = {effX, effY};
    for (int s = 0; s < 3; ++s) {
        if (s < 2) {
            step_c<0><<<RN / 16, 128, 0, stream>>>(cnt, buckets, relencW, Zcur,
                Zp, pp_b, effp, wpp1t, wrp1t, wrp2t, effn[s], Znext[s],
                wnp0t, wnp1t, np_b0, np_b1, np_W2, np_b2, state, (float*)d_out);
            Zcur = Znext[s];
            effp = effn[s];
        } else {
            step_c<1><<<RN / 16, 128, 0, stream>>>(cnt, buckets, relencW, Zcur,
                Zp, pp_b, effp, wpp1t, wrp1t, wrp2t, nullptr, nullptr,
                wnp0t, wnp1t, np_b0, np_b1, np_W2, np_b2, state, (float*)d_out);
        }
    }
}

// Round 16
// 108.999 us; speedup vs baseline: 1.5287x; 1.0388x over previous
//
#include <hip/hip_runtime.h>

#define B 2
#define N_P 2000
#define N_ALL 2048
#define N_REL 8192
#define N_INST 8
#define NF 128
#define DEG_CAP 64

typedef unsigned short u16;
typedef __attribute__((ext_vector_type(8))) short bf16x8;
typedef __attribute__((ext_vector_type(4))) float f32x4;

__device__ __forceinline__ u16 f2bf(float f) {
    union { float f; unsigned u; } v; v.f = f;
    unsigned r = v.u + 0x7FFFu + ((v.u >> 16) & 1u);
    return (u16)(r >> 16);
}
__device__ __forceinline__ float bf2f(u16 h) {
    union { unsigned u; float f; } v; v.u = ((unsigned)h) << 16; return v.f;
}

#define MFMA16(a, b, c) __builtin_amdgcn_mfma_f32_16x16x32_bf16((a), (b), (c), 0, 0, 0)
#define SWZ(row, col) ((col) ^ (((row) & 7) << 3))

#define NWT 13
struct WtCvt {
    const float* src[NWT];
    int K[NWT];
    int Kpad[NWT];
    int cum[NWT + 1];
};

// ---------------------------------------------------------------------------
// chunk scan helper: scan 512 floats at CHUNK offset of row base; returns
// found index or -1, wave-reduced.
// ---------------------------------------------------------------------------
__device__ __forceinline__ int scan_chunk512(const float* base, int start, int lane)
{
    const f32x4* s = reinterpret_cast<const f32x4*>(base + start + lane * 8);
    f32x4 v0 = s[0], v1 = s[1];
    int f = -1;
    int bi = start + lane * 8;
    #pragma unroll
    for (int j = 0; j < 4; ++j) {
        if (v0[j] != 0.f) f = bi + j;
        if (v1[j] != 0.f) f = bi + 4 + j;
    }
    #pragma unroll
    for (int off = 32; off; off >>= 1) f = max(f, __shfl_xor(f, off));
    return f;
}

// ---------------------------------------------------------------------------
// D1: scan_q0: [0,8192) rows' first 512 floats unconditional;
//     [8192,8944) weight convert; [8944,8960) p_inputs; [8960,8976) cnt zero.
// ---------------------------------------------------------------------------
#define Q0_SCAN_BLKS 8192
#define Q0_CVT_BLKS  752
#define Q0_PIN_BLKS  16
#define Q0_ZERO_BLKS 16
#define Q0_TOTAL (Q0_SCAN_BLKS + Q0_CVT_BLKS + Q0_PIN_BLKS + Q0_ZERO_BLKS)

__global__ __launch_bounds__(256) void scan_q0(
    const float* __restrict__ Rr, const float* __restrict__ Rs,
    int* __restrict__ rr, int* __restrict__ rs,
    WtCvt d, u16* __restrict__ wt, int wt_total,
    const float* __restrict__ state, const float* __restrict__ attrs,
    const float* __restrict__ action, const float* __restrict__ den,
    const float* __restrict__ phys, u16* __restrict__ P,
    int* __restrict__ cnt)
{
    int blk = blockIdx.x;
    if (blk < Q0_SCAN_BLKS) {
        int lane = threadIdx.x & 63;
        int r = blk * 4 + (threadIdx.x >> 6);          // 0..32767
        const float* base = (r < 16384 ? Rr + (size_t)r * N_ALL
                                       : Rs + (size_t)(r - 16384) * N_ALL);
        int f = scan_chunk512(base, 0, lane);
        if (lane == 0) {
            int* outp = (r < 16384) ? rr : rs;
            outp[r & 16383] = f;
        }
        return;
    }
    blk -= Q0_SCAN_BLKS;
    if (blk < Q0_CVT_BLKS) {
        int t = blk * 256 + threadIdx.x;
        if (t >= wt_total) return;
        int m = 0;
        while (t >= d.cum[m + 1]) m++;
        int loc = t - d.cum[m];
        int Kp = d.Kpad[m];
        int c = loc / Kp, k = loc - c * Kp;
        float v = (k < d.K[m]) ? d.src[m][(size_t)k * NF + c] : 0.f;
        wt[t] = f2bf(v);
        return;
    }
    blk -= Q0_CVT_BLKS;
    if (blk < Q0_PIN_BLKS) {
        int t = blk * 256 + threadIdx.x;
        if (t >= B * N_ALL) return;
        int b = t >> 11, n = t & 2047;
        float o[19];
        o[0] = attrs[t * 2]; o[1] = attrs[t * 2 + 1];
        #pragma unroll
        for (int h = 0; h < 3; ++h)
            #pragma unroll
            for (int c = 0; c < 3; ++c)
                o[2 + h * 3 + c] = state[(((size_t)b * 4 + h + 1) * N_ALL + n) * 3 + c]
                                 - state[(((size_t)b * 4 + h)     * N_ALL + n) * 3 + c];
        #pragma unroll
        for (int c = 0; c < 3; ++c)
            o[11 + c] = state[(((size_t)b * 4 + 3) * N_ALL + n) * 3 + c];
        o[14] = (n < N_P) ? phys[b] : 0.f;
        #pragma unroll
        for (int c = 0; c < 3; ++c) o[15 + c] = action[t * 3 + c];
        o[18] = (n < N_P) ? den[b] : 0.f;
        u16* dst = P + (size_t)t * 32;
        #pragma unroll
        for (int k = 0; k < 19; ++k) dst[k] = f2bf(o[k]);
        #pragma unroll
        for (int k = 19; k < 32; ++k) dst[k] = 0;
        return;
    }
    blk -= Q0_PIN_BLKS;
    {
        int t = blk * 256 + threadIdx.x;
        if (t < B * N_ALL) cnt[t] = 0;
    }
}

// ---------------------------------------------------------------------------
// D2: stripe [512,1024) conditional.
// ---------------------------------------------------------------------------
__global__ __launch_bounds__(256) void scan_s512(
    const float* __restrict__ Rr, const float* __restrict__ Rs,
    int* __restrict__ rr, int* __restrict__ rs)
{
    int lane = threadIdx.x & 63;
    int r = blockIdx.x * 4 + (threadIdx.x >> 6);
    int* outp = (r < 16384) ? rr : rs;
    int e = r & 16383;
    if (outp[e] >= 0) return;
    const float* base = (r < 16384) ? Rr + (size_t)r * N_ALL
                                    : Rs + (size_t)(r - 16384) * N_ALL;
    int f = scan_chunk512(base, 512, lane);
    if (lane == 0) outp[e] = f;
}

// ---------------------------------------------------------------------------
// D3: merged last stripes — chunk [1024,1536), then [1536,2048) only if the
// first found nothing (wave-uniform after reduce; ~12.5% of rows).
// Same-stream serialization guarantees unresolved rows here have their
// nonzero in [1024,2048), so write-always is correct and replay-safe.
// ---------------------------------------------------------------------------
__global__ __launch_bounds__(256) void scan_last(
    const float* __restrict__ Rr, const float* __restrict__ Rs,
    int* __restrict__ rr, int* __restrict__ rs)
{
    int lane = threadIdx.x & 63;
    int r = blockIdx.x * 4 + (threadIdx.x >> 6);
    int* outp = (r < 16384) ? rr : rs;
    int e = r & 16383;
    if (outp[e] >= 0) return;
    const float* base = (r < 16384) ? Rr + (size_t)r * N_ALL
                                    : Rs + (size_t)(r - 16384) * N_ALL;
    int f = scan_chunk512(base, 1024, lane);
    if (f < 0) f = scan_chunk512(base, 1536, lane);
    if (lane == 0) outp[e] = f;
}

// ---------------------------------------------------------------------------
// Layer helpers (wave = 16 rows). ldsA_gemm: full 128 cols; ldsA_gemm4: 64-col
// half starting at colbase.
// ---------------------------------------------------------------------------
__device__ __forceinline__ void ldsA_gemm(const u16* T, const u16* __restrict__ wtm,
                                          f32x4 acc[8], int r16, int g4)
{
    #pragma unroll
    for (int cf = 0; cf < 8; ++cf) acc[cf] = (f32x4){0.f, 0.f, 0.f, 0.f};
    #pragma unroll
    for (int kf = 0; kf < 4; ++kf) {
        int kcol = kf * 32 + g4 * 8;
        bf16x8 a = *reinterpret_cast<const bf16x8*>(&T[r16 * NF + SWZ(r16, kcol)]);
        #pragma unroll
        for (int cf = 0; cf < 8; ++cf) {
            bf16x8 bv = *reinterpret_cast<const bf16x8*>(wtm + (size_t)(cf * 16 + r16) * NF + kcol);
            acc[cf] = MFMA16(a, bv, acc[cf]);
        }
    }
}
__device__ __forceinline__ void ldsA_gemm4(const u16* T, const u16* __restrict__ wtm,
                                           int colbase, f32x4 acc[4], int r16, int g4)
{
    #pragma unroll
    for (int cf = 0; cf < 4; ++cf) acc[cf] = (f32x4){0.f, 0.f, 0.f, 0.f};
    #pragma unroll
    for (int kf = 0; kf < 4; ++kf) {
        int kcol = kf * 32 + g4 * 8;
        bf16x8 a = *reinterpret_cast<const bf16x8*>(&T[r16 * NF + SWZ(r16, kcol)]);
        #pragma unroll
        for (int cf = 0; cf < 4; ++cf) {
            bf16x8 bv = *reinterpret_cast<const bf16x8*>(wtm + (size_t)(colbase + cf * 16 + r16) * NF + kcol);
            acc[cf] = MFMA16(a, bv, acc[cf]);
        }
    }
}
__device__ __forceinline__ void tile_store(u16* T, f32x4 acc[8], const float* __restrict__ bias,
                                           int r16, int g4)
{
    #pragma unroll
    for (int cf = 0; cf < 8; ++cf) {
        float bb = bias[cf * 16 + r16];
        #pragma unroll
        for (int i = 0; i < 4; ++i) {
            int row = g4 * 4 + i, col = cf * 16 + r16;
            T[row * NF + SWZ(row, col)] = f2bf(fmaxf(acc[cf][i] + bb, 0.f));
        }
    }
}

// ---------------------------------------------------------------------------
// ENC2 (128-thread blocks, 32 rows each):
//   [0,512): relation encoder; [512,640): particle encoder + Z precompute;
//   [640,648): bucket fill.
// ---------------------------------------------------------------------------
#define ENC_REL_BLKS 512
#define ENC_PART_BLKS 128
#define ENC_FILL_BLKS 8
#define ENC_TOTAL (ENC_REL_BLKS + ENC_PART_BLKS + ENC_FILL_BLKS)

__global__ __launch_bounds__(128) void enc2(
    const u16* __restrict__ P, const float* __restrict__ attrs,
    const float* __restrict__ p_inst,
    const int* __restrict__ rr, const int* __restrict__ rs,
    const u16* __restrict__ wpe0, const u16* __restrict__ wpe1, const u16* __restrict__ wpe2,
    const float* __restrict__ pb0, const float* __restrict__ pb1, const float* __restrict__ pb2,
    const u16* __restrict__ wre0, const u16* __restrict__ wre1, const u16* __restrict__ wre2,
    const float* __restrict__ rb0, const float* __restrict__ rb1, const float* __restrict__ rb2,
    const float* __restrict__ rp_b, const u16* __restrict__ wrp0t,
    const u16* __restrict__ wpp0t, const u16* __restrict__ wrp1t, const u16* __restrict__ wrp2t,
    u16* __restrict__ penc, u16* __restrict__ relencW,
    float* __restrict__ Zp, u16* __restrict__ Zrs0,
    int* __restrict__ cnt, int2* __restrict__ buckets)
{
    __shared__ u16 ri[32 * 64];            // 4 KB
    __shared__ u16 tw[2][2][16 * NF];      // 16 KB
    int tid = threadIdx.x;
    int blk = blockIdx.x;

    if (blk >= ENC_REL_BLKS + ENC_PART_BLKS) {
        int t = (blk - ENC_REL_BLKS - ENC_PART_BLKS) * 128 + tid;
        for (int e = t; e < B * N_REL; e += ENC_FILL_BLKS * 128) {
            int n = ((e >> 13) << 11) + rr[e];
            int pos = atomicAdd(&cnt[n], 1);
            if (pos < DEG_CAP) {
                int2 v; v.x = e; v.y = ((e >> 13) << 11) + rs[e];
                buckets[(size_t)n * DEG_CAP + pos] = v;
            }
        }
        return;
    }

    int w = tid >> 6, lane = tid & 63;
    int r16 = lane & 15, g4 = lane >> 4;
    u16* T0 = tw[w][0];
    u16* T1 = tw[w][1];
    f32x4 acc[8];

    if (blk < ENC_REL_BLKS) {
        {
            int row = tid >> 2;                  // 0..31
            int q = tid & 3;
            int grow = blk * 32 + row;
            int b = grow >> 13;
            int ir = rr[grow], is_ = rs[grow];
            const u16* pr = P + ((size_t)(b << 11) + ir) * 32;
            const u16* ps = P + ((size_t)(b << 11) + is_) * 32;
            float gd = 0.f;
            if (q == 2) {
                #pragma unroll
                for (int k = 0; k < N_INST; ++k) {
                    float gr = (ir < N_P) ? p_inst[((size_t)b * N_P + ir) * N_INST + k] : 0.f;
                    float gs = (is_ < N_P) ? p_inst[((size_t)b * N_P + is_) * N_INST + k] : 0.f;
                    gd += fabsf(gr - gs);
                }
            }
            #pragma unroll
            for (int j = 0; j < 16; ++j) {
                int c = q * 16 + j;
                u16 hv;
                if (c < 19)       hv = pr[c];
                else if (c < 38)  hv = ps[c - 19];
                else if (c < 40)  hv = f2bf(attrs[((size_t)(b << 11) + ir) * 2 + (c - 38)]);
                else if (c < 42)  hv = f2bf(attrs[((size_t)(b << 11) + is_) * 2 + (c - 40)]);
                else if (c == 42) hv = f2bf(gd);
                else if (c < 55)  hv = f2bf(bf2f(pr[c - 41]) - bf2f(ps[c - 41]));
                else if (c == 55) hv = f2bf(bf2f(pr[18]) - bf2f(ps[18]));
                else              hv = 0;
                ri[row * 64 + SWZ(row, c)] = hv;
            }
        }
        __syncthreads();
        int rbase = blk * 32 + w * 16;
        #pragma unroll
        for (int cf = 0; cf < 8; ++cf) acc[cf] = (f32x4){0.f, 0.f, 0.f, 0.f};
        #pragma unroll
        for (int kf = 0; kf < 2; ++kf) {
            int kcol = kf * 32 + g4 * 8;
            int lr = w * 16 + r16;
            bf16x8 a = *reinterpret_cast<const bf16x8*>(&ri[lr * 64 + SWZ(lr, kcol)]);
            #pragma unroll
            for (int cf = 0; cf < 8; ++cf) {
                bf16x8 bv = *reinterpret_cast<const bf16x8*>(wre0 + (size_t)(cf * 16 + r16) * 64 + kcol);
                acc[cf] = MFMA16(a, bv, acc[cf]);
            }
        }
        tile_store(T0, acc, rb0, r16, g4);
        ldsA_gemm(T0, wre1, acc, r16, g4);
        tile_store(T1, acc, rb1, r16, g4);
        ldsA_gemm(T1, wre2, acc, r16, g4);
        tile_store(T0, acc, rb2, r16, g4);
        ldsA_gemm(T0, wrp0t, acc, r16, g4);
        #pragma unroll
        for (int cf = 0; cf < 8; ++cf) {
            float bb = rp_b[cf * 16 + r16];
            #pragma unroll
            for (int i = 0; i < 4; ++i) {
                int grow = rbase + g4 * 4 + i;
                relencW[(size_t)grow * NF + cf * 16 + r16] = f2bf(acc[cf][i] + bb);
            }
        }
        return;
    }

    int blk2 = blk - ENC_REL_BLKS;
    int rbase = blk2 * 32 + w * 16;
    #pragma unroll
    for (int cf = 0; cf < 8; ++cf) acc[cf] = (f32x4){0.f, 0.f, 0.f, 0.f};
    {
        int kcol = g4 * 8;
        bf16x8 a = *reinterpret_cast<const bf16x8*>(P + (size_t)(rbase + r16) * 32 + kcol);
        #pragma unroll
        for (int cf = 0; cf < 8; ++cf) {
            bf16x8 bv = *reinterpret_cast<const bf16x8*>(wpe0 + (size_t)(cf * 16 + r16) * 32 + kcol);
            acc[cf] = MFMA16(a, bv, acc[cf]);
        }
    }
    tile_store(T0, acc, pb0, r16, g4);
    ldsA_gemm(T0, wpe1, acc, r16, g4);
    tile_store(T1, acc, pb1, r16, g4);
    ldsA_gemm(T1, wpe2, acc, r16, g4);
    tile_store(T0, acc, pb2, r16, g4);
    #pragma unroll
    for (int cf = 0; cf < 8; ++cf)
        #pragma unroll
        for (int i = 0; i < 4; ++i) {
            int row = g4 * 4 + i, col = cf * 16 + r16;
            penc[(size_t)(rbase + row) * NF + col] = T0[row * NF + SWZ(row, col)];
        }
    ldsA_gemm(T0, wpp0t, acc, r16, g4);
    #pragma unroll
    for (int cf = 0; cf < 8; ++cf)
        #pragma unroll
        for (int i = 0; i < 4; ++i)
            Zp[(size_t)(rbase + g4 * 4 + i) * NF + cf * 16 + r16] = acc[cf][i];
    ldsA_gemm(T0, wrp1t, acc, r16, g4);
    #pragma unroll
    for (int cf = 0; cf < 8; ++cf)
        #pragma unroll
        for (int i = 0; i < 4; ++i)
            Zrs0[(size_t)(rbase + g4 * 4 + i) * 256 + cf * 16 + r16] = f2bf(acc[cf][i]);
    ldsA_gemm(T0, wrp2t, acc, r16, g4);
    #pragma unroll
    for (int cf = 0; cf < 8; ++cf)
        #pragma unroll
        for (int i = 0; i < 4; ++i)
            Zrs0[(size_t)(rbase + g4 * 4 + i) * 256 + 128 + cf * 16 + r16] = f2bf(acc[cf][i]);
}

// ---------------------------------------------------------------------------
// STEP_C (128-thread blocks, 16 nodes each, 256 blocks) — unchanged from R15.
// ---------------------------------------------------------------------------
template<int LAST>
__global__ __launch_bounds__(128) void step_c(
    const int* __restrict__ cnt, const int2* __restrict__ buckets,
    const u16* __restrict__ relencW, const u16* __restrict__ Zrs,
    const float* __restrict__ Zp, const float* __restrict__ pp_b,
    const u16* __restrict__ eff_prev,
    const u16* __restrict__ wpp1t, const u16* __restrict__ wrp1t, const u16* __restrict__ wrp2t,
    u16* __restrict__ eff_out, u16* __restrict__ Zrs_out,
    const u16* __restrict__ wnp0t, const u16* __restrict__ wnp1t,
    const float* __restrict__ nb0, const float* __restrict__ nb1,
    const float* __restrict__ np_W2, const float* __restrict__ nb2,
    const float* __restrict__ state, float* __restrict__ out)
{
    __shared__ float aggL[16][NF];
    __shared__ u16 T0s[16 * NF];
    __shared__ u16 T1s[16 * NF];
    int tid = threadIdx.x;
    int w = tid >> 6, lane = tid & 63;
    int r16 = lane & 15, g4 = lane >> 4;
    int nbase = blockIdx.x * 16;

    {
        int ln = tid >> 3;
        int q  = tid & 7;
        int n  = nbase + ln;
        const u16* zrp = Zrs + (size_t)n * 256 + q * 16;
        bf16x8 z0 = *reinterpret_cast<const bf16x8*>(zrp);
        bf16x8 z1 = *reinterpret_cast<const bf16x8*>(zrp + 8);
        float zr[16];
        #pragma unroll
        for (int j = 0; j < 8; ++j) { zr[j] = bf2f((u16)z0[j]); zr[8 + j] = bf2f((u16)z1[j]); }
        float a16[16];
        #pragma unroll
        for (int j = 0; j < 16; ++j) a16[j] = 0.f;
        int k1 = min(cnt[n], DEG_CAP);
        const int2* eb_base = buckets + (size_t)n * DEG_CAP;
        for (int k = 0; k < k1; k += 4) {
            int m = k1 - k;
            int2 eb[4];
            #pragma unroll
            for (int t = 0; t < 4; ++t) if (t < m) eb[t] = eb_base[k + t];
            #pragma unroll
            for (int t = 0; t < 4; ++t) if (t < m) {
                const u16* rwp = relencW + (size_t)eb[t].x * NF + q * 16;
                const u16* zsp = Zrs + (size_t)eb[t].y * 256 + 128 + q * 16;
                bf16x8 rw0 = *reinterpret_cast<const bf16x8*>(rwp);
                bf16x8 rw1 = *reinterpret_cast<const bf16x8*>(rwp + 8);
                bf16x8 zs0 = *reinterpret_cast<const bf16x8*>(zsp);
                bf16x8 zs1 = *reinterpret_cast<const bf16x8*>(zsp + 8);
                #pragma unroll
                for (int j = 0; j < 8; ++j) {
                    a16[j]     += fmaxf(bf2f((u16)rw0[j]) + zr[j]     + bf2f((u16)zs0[j]), 0.f);
                    a16[8 + j] += fmaxf(bf2f((u16)rw1[j]) + zr[8 + j] + bf2f((u16)zs1[j]), 0.f);
                }
            }
        }
        int c0 = q * 16;
        int pc0 = c0 ^ ((ln & 7) << 3);
        int pc1 = (c0 + 8) ^ ((ln & 7) << 3);
        #pragma unroll
        for (int j = 0; j < 8; ++j) {
            aggL[ln][pc0 + j] = a16[j];
            aggL[ln][pc1 + j] = a16[8 + j];
        }
    }
    __syncthreads();

    int cb = w * 64;
    f32x4 acc[4];
    #pragma unroll
    for (int cf = 0; cf < 4; ++cf) acc[cf] = (f32x4){0.f, 0.f, 0.f, 0.f};
    #pragma unroll
    for (int kf = 0; kf < 4; ++kf) {
        int kcol = kf * 32 + g4 * 8;
        int pc = kcol ^ ((r16 & 7) << 3);
        float4 lo = *reinterpret_cast<const float4*>(&aggL[r16][pc]);
        float4 hi = *reinterpret_cast<const float4*>(&aggL[r16][pc + 4]);
        bf16x8 a;
        a[0] = (short)f2bf(lo.x); a[1] = (short)f2bf(lo.y);
        a[2] = (short)f2bf(lo.z); a[3] = (short)f2bf(lo.w);
        a[4] = (short)f2bf(hi.x); a[5] = (short)f2bf(hi.y);
        a[6] = (short)f2bf(hi.z); a[7] = (short)f2bf(hi.w);
        #pragma unroll
        for (int cf = 0; cf < 4; ++cf) {
            bf16x8 bv = *reinterpret_cast<const bf16x8*>(wpp1t + (size_t)(cb + cf * 16 + r16) * NF + kcol);
            acc[cf] = MFMA16(a, bv, acc[cf]);
        }
    }
    #pragma unroll
    for (int cf = 0; cf < 4; ++cf) {
        int col = cb + cf * 16 + r16;
        float bb = pp_b[col];
        #pragma unroll
        for (int i = 0; i < 4; ++i) {
            int trow = g4 * 4 + i;
            int grow = nbase + trow;
            float v = acc[cf][i] + bb + Zp[(size_t)grow * NF + col]
                    + bf2f(eff_prev[(size_t)grow * NF + col]);
            u16 hv = f2bf(fmaxf(v, 0.f));
            T0s[trow * NF + SWZ(trow, col)] = hv;
            if (!LAST) eff_out[(size_t)grow * NF + col] = hv;
        }
    }
    __syncthreads();

    if (!LAST) {
        f32x4 a2[4];
        ldsA_gemm4(T0s, wrp1t, cb, a2, r16, g4);
        #pragma unroll
        for (int cf = 0; cf < 4; ++cf)
            #pragma unroll
            for (int i = 0; i < 4; ++i)
                Zrs_out[(size_t)(nbase + g4 * 4 + i) * 256 + cb + cf * 16 + r16] = f2bf(a2[cf][i]);
        ldsA_gemm4(T0s, wrp2t, cb, a2, r16, g4);
        #pragma unroll
        for (int cf = 0; cf < 4; ++cf)
            #pragma unroll
            for (int i = 0; i < 4; ++i)
                Zrs_out[(size_t)(nbase + g4 * 4 + i) * 256 + 128 + cb + cf * 16 + r16] = f2bf(a2[cf][i]);
    } else {
        f32x4 a2[4];
        ldsA_gemm4(T0s, wnp0t, cb, a2, r16, g4);
        #pragma unroll
        for (int cf = 0; cf < 4; ++cf) {
            float bb = nb0[cb + cf * 16 + r16];
            #pragma unroll
            for (int i = 0; i < 4; ++i) {
                int row = g4 * 4 + i, col = cb + cf * 16 + r16;
                T1s[row * NF + SWZ(row, col)] = f2bf(fmaxf(a2[cf][i] + bb, 0.f));
            }
        }
        __syncthreads();
        ldsA_gemm4(T1s, wnp1t, cb, a2, r16, g4);
        #pragma unroll
        for (int cf = 0; cf < 4; ++cf) {
            float bb = nb1[cb + cf * 16 + r16];
            #pragma unroll
            for (int i = 0; i < 4; ++i) {
                int row = g4 * 4 + i, col = cb + cf * 16 + r16;
                T0s[row * NF + SWZ(row, col)] = f2bf(fmaxf(a2[cf][i] + bb, 0.f));
            }
        }
        __syncthreads();
        if (w == 0 && g4 < 3) {
            int grow = nbase + r16;
            int b = grow >> 11, n = grow & 2047;
            if (n < N_P) {
                float s = nb2[g4];
                for (int k = 0; k < NF; ++k)
                    s += bf2f(T0s[r16 * NF + SWZ(r16, k)]) * np_W2[k * 3 + g4];
                s = fminf(fmaxf(s, -100.f), 100.f);
                out[((size_t)b * N_P + n) * 3 + g4] =
                    s + state[(((size_t)b * 4 + 3) * N_ALL + n) * 3 + g4];
            }
        }
    }
}

// ---------------------------------------------------------------------------
extern "C" void kernel_launch(void* const* d_in, const int* in_sizes, int n_in,
                              void* d_out, int out_size, void* d_ws, size_t ws_size,
                              hipStream_t stream) {
    (void)in_sizes; (void)n_in; (void)out_size; (void)ws_size;
    const float* state      = (const float*)d_in[0];
    const float* attrs      = (const float*)d_in[1];
    const float* Rr         = (const float*)d_in[2];
    const float* Rs         = (const float*)d_in[3];
    const float* p_instance = (const float*)d_in[4];
    const float* action     = (const float*)d_in[5];
    const float* den        = (const float*)d_in[6];
    const float* phys       = (const float*)d_in[7];
    const float* pe_W0 = (const float*)d_in[8];  const float* pe_b0 = (const float*)d_in[9];
    const float* pe_W1 = (const float*)d_in[10]; const float* pe_b1 = (const float*)d_in[11];
    const float* pe_W2 = (const float*)d_in[12]; const float* pe_b2 = (const float*)d_in[13];
    const float* re_W0 = (const float*)d_in[14]; const float* re_b0 = (const float*)d_in[15];
    const float* re_W1 = (const float*)d_in[16]; const float* re_b1 = (const float*)d_in[17];
    const float* re_W2 = (const float*)d_in[18]; const float* re_b2 = (const float*)d_in[19];
    const float* pp_W  = (const float*)d_in[20]; const float* pp_b  = (const float*)d_in[21];
    const float* rp_W  = (const float*)d_in[22]; const float* rp_b  = (const float*)d_in[23];
    const float* np_W0 = (const float*)d_in[24]; const float* np_b0 = (const float*)d_in[25];
    const float* np_W1 = (const float*)d_in[26]; const float* np_b1 = (const float*)d_in[27];
    const float* np_W2 = (const float*)d_in[28]; const float* np_b2 = (const float*)d_in[29];

    char* base = (char*)d_ws;
    size_t off = 0;
    auto alloc = [&](size_t bytes) -> void* {
        off = (off + 255) & ~(size_t)255;
        void* p = base + off; off += bytes; return p;
    };
    const int RN = B * N_ALL;    // 4096
    const int RE = B * N_REL;    // 16384
    int*   rr      = (int*)alloc(RE * 4);
    int*   rs      = (int*)alloc(RE * 4);
    int*   cnt     = (int*)alloc(RN * 4);
    int2*  buckets = (int2*)alloc((size_t)RN * DEG_CAP * 8);
    u16*   P       = (u16*)alloc((size_t)RN * 32 * 2);
    u16*   penc    = (u16*)alloc((size_t)RN * NF * 2);
    u16*   relencW = (u16*)alloc((size_t)RE * NF * 2);
    float* Zp      = (float*)alloc((size_t)RN * NF * 4);
    u16*   ZrsA    = (u16*)alloc((size_t)RN * 256 * 2);
    u16*   ZrsB    = (u16*)alloc((size_t)RN * 256 * 2);
    u16*   effX    = (u16*)alloc((size_t)RN * NF * 2);
    u16*   effY    = (u16*)alloc((size_t)RN * NF * 2);

    WtCvt d;
    const float* srcs[NWT] = {pe_W0, pe_W1, pe_W2, re_W0, re_W1, re_W2,
                              rp_W, rp_W + 128 * NF, rp_W + 256 * NF,
                              pp_W, pp_W + 128 * NF, np_W0, np_W1};
    const int Ks[NWT]  = {19, 128, 128, 56, 128, 128, 128, 128, 128, 128, 128, 128, 128};
    const int Kps[NWT] = {32, 128, 128, 64, 128, 128, 128, 128, 128, 128, 128, 128, 128};
    d.cum[0] = 0;
    for (int i = 0; i < NWT; ++i) {
        d.src[i] = srcs[i]; d.K[i] = Ks[i]; d.Kpad[i] = Kps[i];
        d.cum[i + 1] = d.cum[i] + NF * Kps[i];
    }
    int wt_total = d.cum[NWT];
    u16* wt = (u16*)alloc((size_t)wt_total * 2);
    const u16 *wpe0 = wt + d.cum[0], *wpe1 = wt + d.cum[1], *wpe2 = wt + d.cum[2];
    const u16 *wre0 = wt + d.cum[3], *wre1 = wt + d.cum[4], *wre2 = wt + d.cum[5];
    const u16 *wrp0t = wt + d.cum[6], *wrp1t = wt + d.cum[7], *wrp2t = wt + d.cum[8];
    const u16 *wpp0t = wt + d.cum[9], *wpp1t = wt + d.cum[10];
    const u16 *wnp0t = wt + d.cum[11], *wnp1t = wt + d.cum[12];

    scan_q0<<<Q0_TOTAL, 256, 0, stream>>>(Rr, Rs, rr, rs, d, wt, wt_total,
                                          state, attrs, action, den, phys, P, cnt);
    scan_s512<<<8192, 256, 0, stream>>>(Rr, Rs, rr, rs);
    scan_last<<<8192, 256, 0, stream>>>(Rr, Rs, rr, rs);

    enc2<<<ENC_TOTAL, 128, 0, stream>>>(P, attrs, p_instance, rr, rs,
        wpe0, wpe1, wpe2, pe_b0, pe_b1, pe_b2,
        wre0, wre1, wre2, re_b0, re_b1, re_b2,
        rp_b, wrp0t, wpp0t, wrp1t, wrp2t,
        penc, relencW, Zp, ZrsA, cnt, buckets);

    const u16* Zcur = ZrsA;
    const u16* effp = penc;
    u16* Znext[2] = {ZrsB, ZrsA};
    u16* effn[2]  = {effX, effY};
    for (int s = 0; s < 3; ++s) {
        if (s < 2) {
            step_c<0><<<RN / 16, 128, 0, stream>>>(cnt, buckets, relencW, Zcur,
                Zp, pp_b, effp, wpp1t, wrp1t, wrp2t, effn[s], Znext[s],
                wnp0t, wnp1t, np_b0, np_b1, np_W2, np_b2, state, (float*)d_out);
            Zcur = Znext[s];
            effp = effn[s];
        } else {
            step_c<1><<<RN / 16, 128, 0, stream>>>(cnt, buckets, relencW, Zcur,
                Zp, pp_b, effp, wpp1t, wrp1t, wrp2t, nullptr, nullptr,
                wnp0t, wnp1t, np_b0, np_b1, np_W2, np_b2, state, (float*)d_out);
        }
    }
}